// Round 10
// baseline (239.999 us; speedup 1.0000x reference)
//
#include <hip/hip_runtime.h>

#define NB 8
#define NS 2048
#define ND 256
#define NH 4
#define NHD 64
#define ND2 512
#define NM (NB * NS)
#define C1 0.18033688f      // 0.125 * log2(e), prefolded into Q weights/bias

typedef __attribute__((ext_vector_type(8))) short          bf16x8;
typedef __attribute__((ext_vector_type(4))) float          f32x4;
typedef __attribute__((ext_vector_type(16))) float         f32x16;
typedef unsigned short ushort_t;
typedef unsigned int   uint_t;

#define MFMA16(a, b, c) __builtin_amdgcn_mfma_f32_16x16x32_bf16(a, b, c, 0, 0, 0)
#define MFMA32(a, b, c) __builtin_amdgcn_mfma_f32_32x32x16_bf16(a, b, c, 0, 0, 0)

#if __has_builtin(__builtin_amdgcn_exp2f)
#define EXP2(x) __builtin_amdgcn_exp2f(x)
#else
#define EXP2(x) exp2f(x)
#endif

static __device__ inline uint_t pack2bf(float a, float b) {
    union { float f; uint_t u; } x, y; x.f = a; y.f = b;
    return __builtin_amdgcn_perm(y.u + 0x8000u, x.u + 0x8000u, 0x07060302u);
}
static __device__ inline ushort_t f2bf(float f) {
    union { float f; uint_t u; } x; x.f = f;
    return (ushort_t)((x.u + 0x7FFFu + ((x.u >> 16) & 1u)) >> 16);
}
// single-instruction packed f32->bf16 pair (RNE); elem0 = a, elem1 = b
static __device__ inline uint_t cvtpk_bf16(float a, float b) {
    uint_t r;
    asm("v_cvt_pk_bf16_f32 %0, %1, %2" : "=v"(r) : "v"(a), "v"(b));
    return r;
}
// a' = {a.lo32lanes, b.lo32lanes}; b' = {a.hi32lanes, b.hi32lanes}
static __device__ inline void plswap(uint_t &a, uint_t &b) {
    asm("v_permlane32_swap_b32 %0, %1" : "+v"(a), "+v"(b));
}

// ===========================================================================
// Fragment-major layout: matrix Mat[R][C] stored so the MFMA fragment
// (lane lq=l&15 holds Mat[r16*16+lq][kc*32+(l>>4)*8+j]) is one coalesced
// 16B/lane load: elem = ((r16*(C/32)+kc)*64 + lane)*8 + j.
// ===========================================================================

static __device__ inline void femit(ushort_t* buf, int n, int k, float v) {
    const int kc = k >> 5;
    const int lane = (((k >> 3) & 3) << 4) | (n & 15);
    const int j = k & 7;
    buf[((size_t)(((n >> 4) * 16 + kc) * 64 + lane)) * 8 + j] = f2bf(v);
}

// ---------------------------------------------------------------------------
// ONE fused prep dispatch (all parts independent; switch on block range):
//  [0,4096)    conv: desc/src fp32 -> frag-major bf16
//  [4096,4352) wfrag: q/k/v/m1 weights -> frag-major bf16 W^T (Q scaled C1)
//  [4352,4354) mask -> packed bitmask (512 u32 words, 1 bit/key)
//  [4354,4386) fuse_w: F = o_w@m0b folded with BN -> m0fF. 8 rows/block
//              (32 blocks): m0_w lower half read once per block -> 16MB
//              total (was 128MB at 1 row/block), 16 independent FMA chains.
//  [4386,4402) bias_f: fused MLP0 bias (8 lanes per n + shfl reduce)
// ---------------------------------------------------------------------------
__global__ __launch_bounds__(256) void prep(
    const float* __restrict__ desc, const float* __restrict__ srcp,
    const int* __restrict__ mask,
    const float* __restrict__ q_w, const float* __restrict__ k_w,
    const float* __restrict__ v_w, const float* __restrict__ m1_w,
    const float* __restrict__ o_w, const float* __restrict__ o_b,
    const float* __restrict__ m0_w, const float* __restrict__ m0_b,
    const float* __restrict__ bng, const float* __restrict__ bnb,
    const float* __restrict__ bnm, const float* __restrict__ bnv,
    ushort_t* __restrict__ descF, ushort_t* __restrict__ srcF,
    ushort_t* __restrict__ qwF, ushort_t* __restrict__ kwF,
    ushort_t* __restrict__ vwF, ushort_t* __restrict__ m1F,
    ushort_t* __restrict__ m0fF, float* __restrict__ biasf,
    uint_t* __restrict__ mbits)
{
    __shared__ float ow8[8][256];
    const int blk = blockIdx.x;
    const int t = threadIdx.x;

    if (blk < 4096) {
        // ---- activations fp32 -> frag-major bf16 ----
        const int y = blk >> 11, x = blk & 2047;
        const float* src = y ? srcp : desc;
        ushort_t* dst    = y ? srcF : descF;
        const int g = x * 256 + t;
        const int lane = g & 63, ci = g >> 6;
        const int kc = ci & 7, r16 = ci >> 3;
        const int row = r16 * 16 + (lane & 15);
        const int c0  = kc * 32 + (lane >> 4) * 8;
        const float* p = src + (size_t)row * ND + c0;
        float4 a = *(const float4*)p;
        float4 b = *(const float4*)(p + 4);
        uint4 pk;
        pk.x = pack2bf(a.x, a.y); pk.y = pack2bf(a.z, a.w);
        pk.z = pack2bf(b.x, b.y); pk.w = pack2bf(b.z, b.w);
        *(uint4*)(dst + (size_t)g * 8) = pk;
    } else if (blk < 4352) {
        // ---- weight transpose/convert ----
        const int wb = blk - 4096;
        const int y = wb >> 6, x = wb & 63;
        const float* src; ushort_t* dst; int K, N; float sc = 1.0f;
        switch (y) {
            case 0: src = q_w; dst = qwF; K = 256; N = 256; sc = C1; break;
            case 1: src = k_w; dst = kwF; K = 256; N = 256; break;
            case 2: src = v_w; dst = vwF; K = 256; N = 256; break;
            default: src = m1_w; dst = m1F; K = 512; N = 256; break;
        }
        const int g = x * 256 + t;
        if (g >= (N * K) / 8) return;
        const int lane = g & 63, ci = g >> 6;
        const int lgck = (K == 512) ? 4 : 3;
        const int kc = ci & ((1 << lgck) - 1), n16 = ci >> lgck;
        const int n  = n16 * 16 + (lane & 15);
        const int k0 = kc * 32 + (lane >> 4) * 8;
        float f[8];
#pragma unroll
        for (int j = 0; j < 8; j++) f[j] = src[(size_t)(k0 + j) * N + n] * sc;
        uint4 pk;
        pk.x = pack2bf(f[0], f[1]); pk.y = pack2bf(f[2], f[3]);
        pk.z = pack2bf(f[4], f[5]); pk.w = pack2bf(f[6], f[7]);
        *(uint4*)(dst + (size_t)g * 8) = pk;
    } else if (blk < 4354) {
        // ---- mask -> bitmask: word g covers keys [g*32, g*32+32) ----
        const int g = (blk - 4352) * 256 + t;   // [0, 512)
        const int base = g * 32;
        uint_t m = 0;
#pragma unroll
        for (int j = 0; j < 32; j++) m |= (mask[base + j] ? 1u : 0u) << j;
        mbits[g] = m;
    } else if (blk < 4386) {
        // ---- fused MLP0 weight, 8 o_w rows per block (32 blocks) ----
        const int i0 = (blk - 4354) * 8;
#pragma unroll
        for (int r = 0; r < 8; r++) ow8[r][t] = o_w[(i0 + r) * 256 + t];
        __syncthreads();
        float f0[8], f1[8];
#pragma unroll
        for (int r = 0; r < 8; r++) { f0[r] = 0.f; f1[r] = 0.f; }
#pragma unroll 2
        for (int j = 0; j < 256; j++) {
            const float w0 = m0_w[(size_t)(256 + j) * 512 + t];
            const float w1 = m0_w[(size_t)(256 + j) * 512 + t + 256];
#pragma unroll
            for (int r = 0; r < 8; r++) {
                f0[r] += ow8[r][j] * w0;
                f1[r] += ow8[r][j] * w1;
            }
        }
        const float A0v = bng[t] * rsqrtf(bnv[t] + 1e-5f);
        const float A1v = bng[t + 256] * rsqrtf(bnv[t + 256] + 1e-5f);
#pragma unroll
        for (int r = 0; r < 8; r++) {
            const int i = i0 + r;
            femit(m0fF, t, 256 + i, f0[r] * A0v);
            femit(m0fF, t + 256, 256 + i, f1[r] * A1v);
            femit(m0fF, t, i, m0_w[(size_t)i * 512 + t] * A0v);
            femit(m0fF, t + 256, i, m0_w[(size_t)i * 512 + t + 256] * A1v);
        }
    } else {
        // ---- fused MLP0 bias: 8 lanes per n, shfl-reduce ----
        const int bb = blk - 4386;          // [0,16)
        const int n  = bb * 32 + (t >> 3);
        const int jp = t & 7;
        float s = 0.f;
#pragma unroll 4
        for (int j = jp * 32; j < jp * 32 + 32; j++)
            s += o_b[j] * m0_w[(size_t)(256 + j) * 512 + n];
        s += __shfl_xor(s, 1);
        s += __shfl_xor(s, 2);
        s += __shfl_xor(s, 4);
        if (jp == 0) {
            const float A = bng[n] * rsqrtf(bnv[n] + 1e-5f);
            biasf[n] = (m0_b[n] + s - bnm[n]) * A + bnb[n];
        }
    }
}

// ---------------------------------------------------------------------------
// GEMM core (r4/r7-proven): wave-tile MT*16 tok x 64 ch. All-global
// frag-major, no LDS, no barriers. NO explicit prefetch (r8's reg-dbuf and
// r5's LDS staging both regressed — compiler scheduling already near-best).
// ---------------------------------------------------------------------------
template <int KC, int AK, bool NAT, int MT>
static __device__ inline void core(
    const ushort_t* __restrict__ A0, const ushort_t* __restrict__ A1,
    const ushort_t* __restrict__ WF, int t16, int n16, f32x4 acc[MT][4])
{
    const int lane = threadIdx.x & 63;
#pragma unroll
    for (int kc = 0; kc < KC; kc++) {
        const ushort_t* Ab = (kc < AK) ? A0 : A1;
        const int kca = (kc < AK) ? kc : kc - AK;
        bf16x8 af[MT], wf[4];
#pragma unroll
        for (int mt = 0; mt < MT; mt++)
            af[mt] = *(const bf16x8*)(Ab + ((size_t)((t16 + mt) * AK + kca) * 64 + lane) * 8);
#pragma unroll
        for (int nt = 0; nt < 4; nt++)
            wf[nt] = *(const bf16x8*)(WF + ((size_t)((n16 + nt) * KC + kc) * 64 + lane) * 8);
#pragma unroll
        for (int mt = 0; mt < MT; mt++)
#pragma unroll
            for (int nt = 0; nt < 4; nt++) {
                if (NAT) acc[mt][nt] = MFMA16(af[mt], wf[nt], acc[mt][nt]);
                else     acc[mt][nt] = MFMA16(wf[nt], af[mt], acc[mt][nt]);
            }
    }
}

// ---------------------------------------------------------------------------
// fused QKV — r4 tiles (MT=4, 256 tok/block) + T1 XCD swizzle.
// 1D grid 768. L=(F%8)*96+F/8 (bijective): XCD k gets L in [96k,96k+96) =
// 8 token-panels x (4 heads x 3 z). All 12 blocks sharing a token panel sit
// on ONE XCD -> A panel L2-local after first read; W (384KB) L2-resident.
// ---------------------------------------------------------------------------
__global__ __launch_bounds__(256) void qkv_frag(
    const ushort_t* __restrict__ descF, const ushort_t* __restrict__ srcF,
    const ushort_t* __restrict__ qwF, const ushort_t* __restrict__ kwF,
    const ushort_t* __restrict__ vwF,
    const float* __restrict__ q_b, const float* __restrict__ k_b,
    const float* __restrict__ v_b,
    ushort_t* __restrict__ qF, ushort_t* __restrict__ kF,
    ushort_t* __restrict__ vF)
{
    const int t = threadIdx.x, w = t >> 6;
    const int lq = t & 15, lg = (t & 63) >> 4;
    const int F = blockIdx.x;                   // [0,768)
    const int L = (F & 7) * 96 + (F >> 3);
    const int m = L % 96;
    const int yy = m / 12, r = m % 12;
    const int h = r & 3, z = r >> 2;            // head, {q,k,v}
    const int y = (L / 96) * 8 + yy;            // token panel [0,64)
    const int tok0 = (y << 8) + (w << 6);
    const int t16  = tok0 >> 4, n16 = h << 2;

    f32x4 acc[4][4];
#pragma unroll
    for (int mt = 0; mt < 4; mt++)
#pragma unroll
        for (int nt = 0; nt < 4; nt++) acc[mt][nt] = (f32x4){0.f, 0.f, 0.f, 0.f};

    if (z == 2) {
        core<8, 8, true, 4>(srcF, srcF, vwF, t16, n16, acc);
#pragma unroll
        for (int nt = 0; nt < 4; nt++) {
            const int dvh = nt * 16 + lq;
            const float bs = v_b[h * 64 + dvh];
#pragma unroll
            for (int mt = 0; mt < 4; mt++) {
                const int tok = tok0 + mt * 16 + lg * 4;
                const int b = tok >> 11, s0 = tok & 2047;
                const int bh = b * NH + h;
                uint2 pv;
                pv.x = pack2bf(acc[mt][nt][0] + bs, acc[mt][nt][1] + bs);
                pv.y = pack2bf(acc[mt][nt][2] + bs, acc[mt][nt][3] + bs);
                const size_t e = (size_t)bh * 131072 +
                    ((size_t)((dvh >> 4) * 64 + (s0 >> 5)) * 64 +
                     (((s0 >> 3) & 3) * 16 + (dvh & 15))) * 8 + (s0 & 7);
                *(uint2*)(vF + e) = pv;
            }
        }
    } else {
        const ushort_t* A = z ? srcF : descF;
        const ushort_t* W = z ? kwF : qwF;
        const float* bias = z ? k_b : q_b;
        ushort_t* dst     = z ? kF : qF;
        const float bsc   = z ? 1.0f : C1;
        core<8, 8, false, 4>(A, A, W, t16, n16, acc);
#pragma unroll
        for (int nt = 0; nt < 4; nt++) {
            const int d0 = nt * 16 + lg * 4;
            f32x4 b4 = *(const f32x4*)(bias + h * 64 + d0);
#pragma unroll
            for (int mt = 0; mt < 4; mt++) {
                const int tok = tok0 + mt * 16 + lq;
                const int b = tok >> 11, s = tok & 2047;
                const int bh = b * NH + h;
                uint2 pv;
                pv.x = pack2bf(acc[mt][nt][0] + b4[0] * bsc,
                               acc[mt][nt][1] + b4[1] * bsc);
                pv.y = pack2bf(acc[mt][nt][2] + b4[2] * bsc,
                               acc[mt][nt][3] + b4[3] * bsc);
                const size_t e = (size_t)bh * 131072 +
                    ((size_t)((s >> 4) * 2 + (d0 >> 5)) * 64 +
                     (((d0 >> 3) & 3) * 16 + lq)) * 8 + (d0 & 7);
                *(uint2*)(dst + e) = pv;
            }
        }
    }
}

// ---------------------------------------------------------------------------
// MLP0 — r4 tiles (MT=4) + T1 XCD swizzle. 1D grid 512. L=(F%8)*64+F/8:
// XCD k gets 8 token-panels x 8 n-tiles; all 8 n-tiles of a panel co-XCD.
// ---------------------------------------------------------------------------
__global__ __launch_bounds__(256) void mlp0_frag(
    const ushort_t* __restrict__ descF, const ushort_t* __restrict__ ctxF,
    const ushort_t* __restrict__ m0fF, const float* __restrict__ biasf,
    ushort_t* __restrict__ hF)
{
    const int t = threadIdx.x, w = t >> 6;
    const int lq = t & 15, lg = (t & 63) >> 4;
    const int F = blockIdx.x;                   // [0,512)
    const int L = (F & 7) * 64 + (F >> 3);
    const int m = L % 64;
    const int yy = m >> 3, nx = m & 7;
    const int y = (L / 64) * 8 + yy;            // token panel [0,64)
    const int n0   = nx << 6;
    const int tok0 = (y << 8) + (w << 6);
    const int t16  = tok0 >> 4, n16 = n0 >> 4;

    f32x4 acc[4][4];
#pragma unroll
    for (int mt = 0; mt < 4; mt++)
#pragma unroll
        for (int nt = 0; nt < 4; nt++) acc[mt][nt] = (f32x4){0.f, 0.f, 0.f, 0.f};

    core<16, 8, false, 4>(descF, ctxF, m0fF, t16, n16, acc);

#pragma unroll
    for (int nt = 0; nt < 4; nt++) {
        const int c0 = n0 + nt * 16 + lg * 4;
        f32x4 b4 = *(const f32x4*)(biasf + c0);
#pragma unroll
        for (int mt = 0; mt < 4; mt++) {
            const int tok = tok0 + mt * 16 + lq;
            uint2 pv;
            pv.x = pack2bf(fmaxf(acc[mt][nt][0] + b4[0], 0.f),
                           fmaxf(acc[mt][nt][1] + b4[1], 0.f));
            pv.y = pack2bf(fmaxf(acc[mt][nt][2] + b4[2], 0.f),
                           fmaxf(acc[mt][nt][3] + b4[3], 0.f));
            const size_t e = ((size_t)((tok >> 4) * 16 + (c0 >> 5)) * 64 +
                              (((c0 >> 3) & 3) * 16 + lq)) * 8 + (c0 & 7);
            *(uint2*)(hF + e) = pv;
        }
    }
}

// ---------------------------------------------------------------------------
// MLP1 — r4 tiles (MT=2) + T1 XCD swizzle. 1D grid 512. L=(F%8)*64+F/8:
// XCD k gets 16 token-panels x 4 n-tiles; all 4 n-tiles of a panel co-XCD.
// ---------------------------------------------------------------------------
__global__ __launch_bounds__(256) void mlp1_frag(
    const ushort_t* __restrict__ hF, const ushort_t* __restrict__ m1F,
    const float* __restrict__ m1_b, float* __restrict__ out)
{
    const int t = threadIdx.x, w = t >> 6;
    const int lq = t & 15, lg = (t & 63) >> 4;
    const int F = blockIdx.x;                   // [0,512)
    const int L = (F & 7) * 64 + (F >> 3);
    const int m = L % 64;
    const int yy = m >> 2, nx = m & 3;
    const int y = (L / 64) * 16 + yy;           // token panel [0,128)
    const int n0   = nx << 6;
    const int tok0 = (y << 7) + (w << 5);
    const int t16  = tok0 >> 4, n16 = n0 >> 4;

    f32x4 acc[2][4];
#pragma unroll
    for (int mt = 0; mt < 2; mt++)
#pragma unroll
        for (int nt = 0; nt < 4; nt++) acc[mt][nt] = (f32x4){0.f, 0.f, 0.f, 0.f};

    core<16, 16, false, 2>(hF, hF, m1F, t16, n16, acc);

#pragma unroll
    for (int nt = 0; nt < 4; nt++) {
        const int c0 = n0 + nt * 16 + lg * 4;
        f32x4 b4 = *(const f32x4*)(m1_b + c0);
#pragma unroll
        for (int mt = 0; mt < 2; mt++) {
            const int tok = tok0 + mt * 16 + lq;
            f32x4 o4;
#pragma unroll
            for (int j = 0; j < 4; j++) o4[j] = acc[mt][nt][j] + b4[j];
            *(f32x4*)(out + (size_t)tok * ND + c0) = o4;
        }
    }
}

// ---------------------------------------------------------------------------
// Flash cross-attention — r4-proven (60.6us): 32x32x16, key-split, bitmask
// via scalar loads, NO vmcnt drain in the loop. Unchanged.
// ---------------------------------------------------------------------------
__global__ __launch_bounds__(256) void attn_frag(
    const ushort_t* __restrict__ qF, const ushort_t* __restrict__ kF,
    const ushort_t* __restrict__ vF, const uint_t* __restrict__ mbits,
    ushort_t* __restrict__ ctxF)
{
    __shared__ f32x4 Ob[2][2][4][64];   // [wq][dt][r1][lane] partial o (16KB)
    __shared__ float Ls[2][64];         // [wq][lane] partial l (0.5KB)

    const int t = threadIdx.x, w = t >> 6, lane = t & 63;
    const int wq = w & 1, kw = w >> 1;
    const int q = lane & 31, h = lane >> 5;
    // swizzle: flat = x + 32y + 128z in [0,1024)
    const int flat = blockIdx.x + (blockIdx.y << 5) + (blockIdx.z << 7);
    const int bh = (flat & 7) + (((flat >> 8) & 3) << 3);  // [0,32)
    const int qb = (flat >> 3) & 31;                        // [0,32)

    const ushort_t* qh = qF + (size_t)bh * 131072;
    const ushort_t* kh = kF + (size_t)bh * 131072;
    const ushort_t* vh = vF + (size_t)bh * 131072;
    const uint_t* mw = mbits + (bh >> 2) * 64 + (kw << 5);  // 32 words/half

    const int qrow0 = qb * 64 + wq * 32;
    const int tok = qrow0 + q;
    const int kbase = kw << 10;          // this wave's key half

    // Q B-frags (st = 0..3): lane holds Q[tok = qrow0+q][ch = st*16 + 8h + j]
    bf16x8 qf[4];
#pragma unroll
    for (int st = 0; st < 4; st++)
        qf[st] = *(const bf16x8*)(qh +
            ((size_t)(((tok >> 4) * 2 + (st >> 1)) * 64 +
                      ((st * 2 + h) & 3) * 16 + (tok & 15))) * 8);

    f32x16 o[2];
#pragma unroll
    for (int dt = 0; dt < 2; dt++)
#pragma unroll
        for (int j = 0; j < 16; j++) o[dt][j] = 0.f;
    float l_part = 0.0f;

    // preload K A-frags for first chunk of this half
    bf16x8 ka[2][4];
#pragma unroll
    for (int kt = 0; kt < 2; kt++)
#pragma unroll
        for (int st = 0; st < 4; st++) {
            const int key = kbase + kt * 32 + q;
            ka[kt][st] = *(const bf16x8*)(kh +
                ((size_t)(((key >> 4) * 2 + (st >> 1)) * 64 +
                          ((st * 2 + h) & 3) * 16 + (key & 15))) * 8);
        }

    for (int k0 = 0; k0 < 1024; k0 += 64) {
        const int key0 = kbase + k0;

        // V A-frags for THIS chunk: issued at top; consumed after softmax
        // (QK + softmax cover the latency; PV's wait is counted, not drain).
        bf16x8 vf[2][4];
#pragma unroll
        for (int dt = 0; dt < 2; dt++)
#pragma unroll
            for (int st = 0; st < 4; st++) {
                const int d = dt * 32 + q;
                vf[dt][st] = *(const bf16x8*)(vh +
                    ((size_t)(((d >> 4) * 64 + (key0 >> 5) + (st >> 1)) * 64 +
                              ((st * 2 + h) & 3) * 16 + (d & 15))) * 8);
            }

        // wave-uniform mask words (scalar loads -> lgkmcnt, NOT vmcnt)
        const uint_t mw0 = mw[(k0 >> 5)];
        const uint_t mw1 = mw[(k0 >> 5) + 1];

        // QK^T: C[key][q], zero C-init. Wait here is for ka (prefetched a
        // full iteration ago) -> counted vmcnt leaves V(i) in flight.
        f32x16 sa[2];
#pragma unroll
        for (int kt = 0; kt < 2; kt++)
#pragma unroll
            for (int j = 0; j < 16; j++) sa[kt][j] = 0.f;

        __builtin_amdgcn_s_setprio(1);
#pragma unroll
        for (int kt = 0; kt < 2; kt++)
#pragma unroll
            for (int st = 0; st < 4; st++)
                sa[kt] = MFMA32(ka[kt][st], qf[st], sa[kt]);
        __builtin_amdgcn_s_setprio(0);

        // in-place prefetch next chunk's K frags (wrap within half);
        // stays in flight across PV, waited (counted) at next QK.
        const int keyn = kbase + ((k0 + 64) & 1023);
#pragma unroll
        for (int kt = 0; kt < 2; kt++)
#pragma unroll
            for (int st = 0; st < 4; st++) {
                const int key = keyn + kt * 32 + q;
                ka[kt][st] = *(const bf16x8*)(kh +
                    ((size_t)(((key >> 4) * 2 + (st >> 1)) * 64 +
                              ((st * 2 + h) & 3) * 16 + (key & 15))) * 8);
            }

        // softmax numerator (no max-subtract: scores bounded), VMEM-free.
        // mask applied multiplicatively (== additive -1e9) behind a
        // wave-uniform fast-path branch; 4 parallel l accumulators.
        float ls0 = 0.f, ls1 = 0.f, ls2 = 0.f, ls3 = 0.f;
        uint_t W[2][4][2];

#define SMAX_BODY(DM)                                                         \
        _Pragma("unroll")                                                     \
        for (int kt = 0; kt < 2; kt++) {                                      \
            _Pragma("unroll")                                                 \
            for (int r1 = 0; r1 < 4; r1++) {                                  \
                _Pragma("unroll")                                             \
                for (int wv = 0; wv < 2; wv++) {                              \
                    float p0 = EXP2(sa[kt][r1 * 4 + wv * 2]);                 \
                    float p1 = EXP2(sa[kt][r1 * 4 + wv * 2 + 1]);             \
                    if (DM) {                                                 \
                        const uint_t mk = (kt ? mw1 : mw0) >> (h * 4);        \
                        if (!((mk >> (r1 * 8 + wv * 2)) & 1u)) p0 = 0.f;      \
                        if (!((mk >> (r1 * 8 + wv * 2)) & 2u)) p1 = 0.f;      \
                    }                                                         \
                    if (kt == 0) { if (wv == 0) ls0 += p0 + p1;               \
                                   else         ls1 += p0 + p1; }             \
                    else         { if (wv == 0) ls2 += p0 + p1;               \
                                   else         ls3 += p0 + p1; }             \
                    W[kt][r1][wv] = cvtpk_bf16(p0, p1);                       \
                }                                                             \
            }                                                                 \
        }

        if (__builtin_expect((mw0 & mw1) != 0xFFFFFFFFu, 0)) {
            SMAX_BODY(1)
        } else {
            SMAX_BODY(0)
        }
#undef SMAX_BODY
        l_part += (ls0 + ls1) + (ls2 + ls3);

        // half-wave exchange: builds all 16 PV B-operand dwords in 8 swaps
#pragma unroll
        for (int kt = 0; kt < 2; kt++)
#pragma unroll
            for (int s1 = 0; s1 < 2; s1++)
#pragma unroll
                for (int wv = 0; wv < 2; wv++)
                    plswap(W[kt][2 * s1][wv], W[kt][2 * s1 + 1][wv]);

        // ctx^T += V^T · P  (waits V(i) counted; K(i+1) stays in flight)
        __builtin_amdgcn_s_setprio(1);
#pragma unroll
        for (int st = 0; st < 4; st++) {
            const int kt = st >> 1, s1 = st & 1;
            union { uint_t u[4]; bf16x8 v; } pb;
            pb.u[0] = W[kt][2 * s1][0];
            pb.u[1] = W[kt][2 * s1][1];
            pb.u[2] = W[kt][2 * s1 + 1][0];
            pb.u[3] = W[kt][2 * s1 + 1][1];
#pragma unroll
            for (int dt = 0; dt < 2; dt++)
                o[dt] = MFMA32(vf[dt][st], pb.v, o[dt]);
        }
        __builtin_amdgcn_s_setprio(0);
    }

    // per-wave l: lane and lane+32 hold complementary key subsets of the half
    l_part += __shfl_xor(l_part, 32);

    // cross-half combine: kw=1 deposits partials, kw=0 reduces + stores
    if (kw) {
#pragma unroll
        for (int dt = 0; dt < 2; dt++)
#pragma unroll
            for (int r1 = 0; r1 < 4; r1++) {
                f32x4 v;
#pragma unroll
                for (int r0 = 0; r0 < 4; r0++) v[r0] = o[dt][r1 * 4 + r0];
                Ob[wq][dt][r1][lane] = v;
            }
        Ls[wq][lane] = l_part;
    }
    __syncthreads();
    if (kw) return;

    const float li = 1.0f / (l_part + Ls[wq][lane]);

    // epilogue: ctx frag-major bf16.  o[dt] reg r = 4*r1 + r0 is
    // (d = r0 + 8*r1 + 4h + 32*dt, q); each (dt,r1) is one aligned uint2.
    const int tok16 = (bh >> 2) * 128 + (tok >> 4);
#pragma unroll
    for (int dt = 0; dt < 2; dt++)
#pragma unroll
        for (int r1 = 0; r1 < 4; r1++) {
            const f32x4 p = Ob[wq][dt][r1][lane];
            const int c = (bh & 3) * 64 + dt * 32 + r1 * 8 + h * 4;
            uint2 pv;
            pv.x = cvtpk_bf16((o[dt][r1 * 4 + 0] + p[0]) * li,
                              (o[dt][r1 * 4 + 1] + p[1]) * li);
            pv.y = cvtpk_bf16((o[dt][r1 * 4 + 2] + p[2]) * li,
                              (o[dt][r1 * 4 + 3] + p[3]) * li);
            const size_t e = ((size_t)(tok16 * 8 + (c >> 5)) * 64 +
                              (((c >> 3) & 3) * 16 + (tok & 15))) * 8 + (c & 7);
            *(uint2*)(ctxF + e) = pv;
        }
}

extern "C" void kernel_launch(void* const* d_in, const int* in_sizes, int n_in,
                              void* d_out, int out_size, void* d_ws, size_t ws_size,
                              hipStream_t stream)
{
    (void)in_sizes; (void)n_in; (void)out_size; (void)ws_size;
    const float* desc = (const float*)d_in[0];
    const float* srcp = (const float*)d_in[1];
    const int*   mask = (const int*)d_in[2];
    const float* q_w  = (const float*)d_in[3];
    const float* q_b  = (const float*)d_in[4];
    const float* k_w  = (const float*)d_in[5];
    const float* k_b  = (const float*)d_in[6];
    const float* v_w  = (const float*)d_in[7];
    const float* v_b  = (const float*)d_in[8];
    const float* o_w  = (const float*)d_in[9];
    const float* o_b  = (const float*)d_in[10];
    const float* m0_w = (const float*)d_in[11];
    const float* m0_b = (const float*)d_in[12];
    const float* bng  = (const float*)d_in[13];
    const float* bnb  = (const float*)d_in[14];
    const float* bnm  = (const float*)d_in[15];
    const float* bnv  = (const float*)d_in[16];
    const float* m1_w = (const float*)d_in[17];
    const float* m1_b = (const float*)d_in[18];
    float* out = (float*)d_out;

    const size_t ASZ = (size_t)NM * ND;
    ushort_t* descF = (ushort_t*)d_ws;
    ushort_t* srcF  = descF + ASZ;
    ushort_t* qF    = descF + 2 * ASZ;
    ushort_t* kF    = descF + 3 * ASZ;
    ushort_t* vF    = descF + 4 * ASZ;
    ushort_t* qwF   = descF + 5 * ASZ;
    ushort_t* kwF   = qwF + 65536;
    ushort_t* vwF   = kwF + 65536;
    ushort_t* m1F   = vwF + 65536;
    ushort_t* m0fF  = m1F + 131072;
    float*    biasf = (float*)(m0fF + 262144);
    uint_t*   mbits = (uint_t*)(biasf + 512);
    ushort_t* ctxF  = srcF;   // src dead after QKV
    ushort_t* hF    = qF;     // q+k dead after attention

    const dim3 blk(256);

    prep<<<dim3(4402), blk, 0, stream>>>(
        desc, srcp, mask, q_w, k_w, v_w, m1_w, o_w, o_b, m0_w, m0_b,
        bng, bnb, bnm, bnv, descF, srcF, qwF, kwF, vwF, m1F, m0fF, biasf, mbits);

    qkv_frag<<<dim3(768), blk, 0, stream>>>(
        descF, srcF, qwF, kwF, vwF, q_b, k_b, v_b, qF, kF, vF);
    attn_frag<<<dim3(NS / 64, NH, NB), blk, 0, stream>>>(qF, kF, vF, mbits, ctxF);
    mlp0_frag<<<dim3(512), blk, 0, stream>>>(descF, ctxF, m0fF, biasf, hF);
    mlp1_frag<<<dim3(512), blk, 0, stream>>>(hF, m1F, m1_b, out);
}

// Round 11
// 222.818 us; speedup vs baseline: 1.0771x; 1.0771x over previous
//
#include <hip/hip_runtime.h>

#define NB 8
#define NS 2048
#define ND 256
#define NH 4
#define NHD 64
#define ND2 512
#define NM (NB * NS)
#define C1 0.18033688f      // 0.125 * log2(e), prefolded into Q weights/bias

typedef __attribute__((ext_vector_type(8))) short          bf16x8;
typedef __attribute__((ext_vector_type(4))) float          f32x4;
typedef __attribute__((ext_vector_type(16))) float         f32x16;
typedef unsigned short ushort_t;
typedef unsigned int   uint_t;

#define MFMA16(a, b, c) __builtin_amdgcn_mfma_f32_16x16x32_bf16(a, b, c, 0, 0, 0)
#define MFMA32(a, b, c) __builtin_amdgcn_mfma_f32_32x32x16_bf16(a, b, c, 0, 0, 0)

#if __has_builtin(__builtin_amdgcn_exp2f)
#define EXP2(x) __builtin_amdgcn_exp2f(x)
#else
#define EXP2(x) exp2f(x)
#endif

static __device__ inline uint_t pack2bf(float a, float b) {
    union { float f; uint_t u; } x, y; x.f = a; y.f = b;
    return __builtin_amdgcn_perm(y.u + 0x8000u, x.u + 0x8000u, 0x07060302u);
}
static __device__ inline ushort_t f2bf(float f) {
    union { float f; uint_t u; } x; x.f = f;
    return (ushort_t)((x.u + 0x7FFFu + ((x.u >> 16) & 1u)) >> 16);
}
// single-instruction packed f32->bf16 pair (RNE); elem0 = a, elem1 = b
static __device__ inline uint_t cvtpk_bf16(float a, float b) {
    uint_t r;
    asm("v_cvt_pk_bf16_f32 %0, %1, %2" : "=v"(r) : "v"(a), "v"(b));
    return r;
}
// a' = {a.lo32lanes, b.lo32lanes}; b' = {a.hi32lanes, b.hi32lanes}
static __device__ inline void plswap(uint_t &a, uint_t &b) {
    asm("v_permlane32_swap_b32 %0, %1" : "+v"(a), "+v"(b));
}

// ===========================================================================
// Fragment-major layout: matrix Mat[R][C] stored so the MFMA fragment
// (lane lq=l&15 holds Mat[r16*16+lq][kc*32+(l>>4)*8+j]) is one coalesced
// 16B/lane load: elem = ((r16*(C/32)+kc)*64 + lane)*8 + j.
// ===========================================================================

static __device__ inline void femit(ushort_t* buf, int n, int k, float v) {
    const int kc = k >> 5;
    const int lane = (((k >> 3) & 3) << 4) | (n & 15);
    const int j = k & 7;
    buf[((size_t)(((n >> 4) * 16 + kc) * 64 + lane)) * 8 + j] = f2bf(v);
}

// ---------------------------------------------------------------------------
// ONE fused prep dispatch (all parts independent; switch on block range):
//  [0,4096)    conv: desc/src fp32 -> frag-major bf16
//  [4096,4352) wfrag: q/k/v/m1 weights -> frag-major bf16 W^T (Q scaled C1)
//  [4352,4354) mask -> packed bitmask (512 u32 words, 1 bit/key)
//  [4354,4610) fuse_w: F = o_w@m0b folded with BN -> m0fF (coalesced).
//              NOTE r9 lesson: tiling this 8-rows/block regressed 14us —
//              the fatter branch raises the WHOLE prep kernel's VGPR/LDS,
//              dropping occupancy of the latency-bound conv blocks.
//  [4610,4626) bias_f: fused MLP0 bias (8 lanes per n + shfl reduce)
// ---------------------------------------------------------------------------
__global__ __launch_bounds__(256) void prep(
    const float* __restrict__ desc, const float* __restrict__ srcp,
    const int* __restrict__ mask,
    const float* __restrict__ q_w, const float* __restrict__ k_w,
    const float* __restrict__ v_w, const float* __restrict__ m1_w,
    const float* __restrict__ o_w, const float* __restrict__ o_b,
    const float* __restrict__ m0_w, const float* __restrict__ m0_b,
    const float* __restrict__ bng, const float* __restrict__ bnb,
    const float* __restrict__ bnm, const float* __restrict__ bnv,
    ushort_t* __restrict__ descF, ushort_t* __restrict__ srcF,
    ushort_t* __restrict__ qwF, ushort_t* __restrict__ kwF,
    ushort_t* __restrict__ vwF, ushort_t* __restrict__ m1F,
    ushort_t* __restrict__ m0fF, float* __restrict__ biasf,
    uint_t* __restrict__ mbits)
{
    __shared__ float ow[256];
    const int blk = blockIdx.x;
    const int t = threadIdx.x;

    if (blk < 4096) {
        // ---- activations fp32 -> frag-major bf16 ----
        const int y = blk >> 11, x = blk & 2047;
        const float* src = y ? srcp : desc;
        ushort_t* dst    = y ? srcF : descF;
        const int g = x * 256 + t;
        const int lane = g & 63, ci = g >> 6;
        const int kc = ci & 7, r16 = ci >> 3;
        const int row = r16 * 16 + (lane & 15);
        const int c0  = kc * 32 + (lane >> 4) * 8;
        const float* p = src + (size_t)row * ND + c0;
        float4 a = *(const float4*)p;
        float4 b = *(const float4*)(p + 4);
        uint4 pk;
        pk.x = pack2bf(a.x, a.y); pk.y = pack2bf(a.z, a.w);
        pk.z = pack2bf(b.x, b.y); pk.w = pack2bf(b.z, b.w);
        *(uint4*)(dst + (size_t)g * 8) = pk;
    } else if (blk < 4352) {
        // ---- weight transpose/convert ----
        const int wb = blk - 4096;
        const int y = wb >> 6, x = wb & 63;
        const float* src; ushort_t* dst; int K, N; float sc = 1.0f;
        switch (y) {
            case 0: src = q_w; dst = qwF; K = 256; N = 256; sc = C1; break;
            case 1: src = k_w; dst = kwF; K = 256; N = 256; break;
            case 2: src = v_w; dst = vwF; K = 256; N = 256; break;
            default: src = m1_w; dst = m1F; K = 512; N = 256; break;
        }
        const int g = x * 256 + t;
        if (g >= (N * K) / 8) return;
        const int lane = g & 63, ci = g >> 6;
        const int lgck = (K == 512) ? 4 : 3;
        const int kc = ci & ((1 << lgck) - 1), n16 = ci >> lgck;
        const int n  = n16 * 16 + (lane & 15);
        const int k0 = kc * 32 + (lane >> 4) * 8;
        float f[8];
#pragma unroll
        for (int j = 0; j < 8; j++) f[j] = src[(size_t)(k0 + j) * N + n] * sc;
        uint4 pk;
        pk.x = pack2bf(f[0], f[1]); pk.y = pack2bf(f[2], f[3]);
        pk.z = pack2bf(f[4], f[5]); pk.w = pack2bf(f[6], f[7]);
        *(uint4*)(dst + (size_t)g * 8) = pk;
    } else if (blk < 4354) {
        // ---- mask -> bitmask: word g covers keys [g*32, g*32+32) ----
        const int g = (blk - 4352) * 256 + t;   // [0, 512)
        const int base = g * 32;
        uint_t m = 0;
#pragma unroll
        for (int j = 0; j < 32; j++) m |= (mask[base + j] ? 1u : 0u) << j;
        mbits[g] = m;
    } else if (blk < 4610) {
        // ---- fused MLP0 weight (coalesced; block = o_w row i) ----
        const int i = blk - 4354;
        ow[t] = o_w[i * 256 + t];
        __syncthreads();
        float f0 = 0.f, f1 = 0.f;
#pragma unroll 4
        for (int j = 0; j < 256; j++) {
            const float w = ow[j];
            f0 += w * m0_w[(size_t)(256 + j) * 512 + t];
            f1 += w * m0_w[(size_t)(256 + j) * 512 + t + 256];
        }
        const float A0v = bng[t] * rsqrtf(bnv[t] + 1e-5f);
        const float A1v = bng[t + 256] * rsqrtf(bnv[t + 256] + 1e-5f);
        femit(m0fF, t, 256 + i, f0 * A0v);
        femit(m0fF, t + 256, 256 + i, f1 * A1v);
        femit(m0fF, t, i, m0_w[(size_t)i * 512 + t] * A0v);
        femit(m0fF, t + 256, i, m0_w[(size_t)i * 512 + t + 256] * A1v);
    } else {
        // ---- fused MLP0 bias: 8 lanes per n, shfl-reduce ----
        const int bb = blk - 4610;          // [0,16)
        const int n  = bb * 32 + (t >> 3);
        const int jp = t & 7;
        float s = 0.f;
#pragma unroll 4
        for (int j = jp * 32; j < jp * 32 + 32; j++)
            s += o_b[j] * m0_w[(size_t)(256 + j) * 512 + n];
        s += __shfl_xor(s, 1);
        s += __shfl_xor(s, 2);
        s += __shfl_xor(s, 4);
        if (jp == 0) {
            const float A = bng[n] * rsqrtf(bnv[n] + 1e-5f);
            biasf[n] = (m0_b[n] + s - bnm[n]) * A + bnb[n];
        }
    }
}

// ---------------------------------------------------------------------------
// GEMM core (r4/r7-proven): wave-tile MT*16 tok x 64 ch. All-global
// frag-major, no LDS, no barriers. NO explicit prefetch (r8's reg-dbuf and
// r5's LDS staging both regressed — compiler scheduling already near-best).
// ---------------------------------------------------------------------------
template <int KC, int AK, bool NAT, int MT>
static __device__ inline void core(
    const ushort_t* __restrict__ A0, const ushort_t* __restrict__ A1,
    const ushort_t* __restrict__ WF, int t16, int n16, f32x4 acc[MT][4])
{
    const int lane = threadIdx.x & 63;
#pragma unroll
    for (int kc = 0; kc < KC; kc++) {
        const ushort_t* Ab = (kc < AK) ? A0 : A1;
        const int kca = (kc < AK) ? kc : kc - AK;
        bf16x8 af[MT], wf[4];
#pragma unroll
        for (int mt = 0; mt < MT; mt++)
            af[mt] = *(const bf16x8*)(Ab + ((size_t)((t16 + mt) * AK + kca) * 64 + lane) * 8);
#pragma unroll
        for (int nt = 0; nt < 4; nt++)
            wf[nt] = *(const bf16x8*)(WF + ((size_t)((n16 + nt) * KC + kc) * 64 + lane) * 8);
#pragma unroll
        for (int mt = 0; mt < MT; mt++)
#pragma unroll
            for (int nt = 0; nt < 4; nt++) {
                if (NAT) acc[mt][nt] = MFMA16(af[mt], wf[nt], acc[mt][nt]);
                else     acc[mt][nt] = MFMA16(wf[nt], af[mt], acc[mt][nt]);
            }
    }
}

// ---------------------------------------------------------------------------
// fused QKV — r4 tiles (MT=4, 256 tok/block) + T1 XCD swizzle.
// 1D grid 768. L=(F%8)*96+F/8 (bijective): XCD k gets L in [96k,96k+96) =
// 8 token-panels x (4 heads x 3 z). All 12 blocks sharing a token panel sit
// on ONE XCD -> A panel L2-local after first read; W (384KB) L2-resident.
// ---------------------------------------------------------------------------
__global__ __launch_bounds__(256) void qkv_frag(
    const ushort_t* __restrict__ descF, const ushort_t* __restrict__ srcF,
    const ushort_t* __restrict__ qwF, const ushort_t* __restrict__ kwF,
    const ushort_t* __restrict__ vwF,
    const float* __restrict__ q_b, const float* __restrict__ k_b,
    const float* __restrict__ v_b,
    ushort_t* __restrict__ qF, ushort_t* __restrict__ kF,
    ushort_t* __restrict__ vF)
{
    const int t = threadIdx.x, w = t >> 6;
    const int lq = t & 15, lg = (t & 63) >> 4;
    const int F = blockIdx.x;                   // [0,768)
    const int L = (F & 7) * 96 + (F >> 3);
    const int m = L % 96;
    const int yy = m / 12, r = m % 12;
    const int h = r & 3, z = r >> 2;            // head, {q,k,v}
    const int y = (L / 96) * 8 + yy;            // token panel [0,64)
    const int tok0 = (y << 8) + (w << 6);
    const int t16  = tok0 >> 4, n16 = h << 2;

    f32x4 acc[4][4];
#pragma unroll
    for (int mt = 0; mt < 4; mt++)
#pragma unroll
        for (int nt = 0; nt < 4; nt++) acc[mt][nt] = (f32x4){0.f, 0.f, 0.f, 0.f};

    if (z == 2) {
        core<8, 8, true, 4>(srcF, srcF, vwF, t16, n16, acc);
#pragma unroll
        for (int nt = 0; nt < 4; nt++) {
            const int dvh = nt * 16 + lq;
            const float bs = v_b[h * 64 + dvh];
#pragma unroll
            for (int mt = 0; mt < 4; mt++) {
                const int tok = tok0 + mt * 16 + lg * 4;
                const int b = tok >> 11, s0 = tok & 2047;
                const int bh = b * NH + h;
                uint2 pv;
                pv.x = pack2bf(acc[mt][nt][0] + bs, acc[mt][nt][1] + bs);
                pv.y = pack2bf(acc[mt][nt][2] + bs, acc[mt][nt][3] + bs);
                const size_t e = (size_t)bh * 131072 +
                    ((size_t)((dvh >> 4) * 64 + (s0 >> 5)) * 64 +
                     (((s0 >> 3) & 3) * 16 + (dvh & 15))) * 8 + (s0 & 7);
                *(uint2*)(vF + e) = pv;
            }
        }
    } else {
        const ushort_t* A = z ? srcF : descF;
        const ushort_t* W = z ? kwF : qwF;
        const float* bias = z ? k_b : q_b;
        ushort_t* dst     = z ? kF : qF;
        const float bsc   = z ? 1.0f : C1;
        core<8, 8, false, 4>(A, A, W, t16, n16, acc);
#pragma unroll
        for (int nt = 0; nt < 4; nt++) {
            const int d0 = nt * 16 + lg * 4;
            f32x4 b4 = *(const f32x4*)(bias + h * 64 + d0);
#pragma unroll
            for (int mt = 0; mt < 4; mt++) {
                const int tok = tok0 + mt * 16 + lq;
                const int b = tok >> 11, s = tok & 2047;
                const int bh = b * NH + h;
                uint2 pv;
                pv.x = pack2bf(acc[mt][nt][0] + b4[0] * bsc,
                               acc[mt][nt][1] + b4[1] * bsc);
                pv.y = pack2bf(acc[mt][nt][2] + b4[2] * bsc,
                               acc[mt][nt][3] + b4[3] * bsc);
                const size_t e = (size_t)bh * 131072 +
                    ((size_t)((s >> 4) * 2 + (d0 >> 5)) * 64 +
                     (((d0 >> 3) & 3) * 16 + lq)) * 8 + (d0 & 7);
                *(uint2*)(dst + e) = pv;
            }
        }
    }
}

// ---------------------------------------------------------------------------
// MLP0 — r4 tiles (MT=4) + T1 XCD swizzle. 1D grid 512. L=(F%8)*64+F/8:
// XCD k gets 8 token-panels x 8 n-tiles; all 8 n-tiles of a panel co-XCD.
// ---------------------------------------------------------------------------
__global__ __launch_bounds__(256) void mlp0_frag(
    const ushort_t* __restrict__ descF, const ushort_t* __restrict__ ctxF,
    const ushort_t* __restrict__ m0fF, const float* __restrict__ biasf,
    ushort_t* __restrict__ hF)
{
    const int t = threadIdx.x, w = t >> 6;
    const int lq = t & 15, lg = (t & 63) >> 4;
    const int F = blockIdx.x;                   // [0,512)
    const int L = (F & 7) * 64 + (F >> 3);
    const int m = L % 64;
    const int yy = m >> 3, nx = m & 7;
    const int y = (L / 64) * 8 + yy;            // token panel [0,64)
    const int n0   = nx << 6;
    const int tok0 = (y << 8) + (w << 6);
    const int t16  = tok0 >> 4, n16 = n0 >> 4;

    f32x4 acc[4][4];
#pragma unroll
    for (int mt = 0; mt < 4; mt++)
#pragma unroll
        for (int nt = 0; nt < 4; nt++) acc[mt][nt] = (f32x4){0.f, 0.f, 0.f, 0.f};

    core<16, 8, false, 4>(descF, ctxF, m0fF, t16, n16, acc);

#pragma unroll
    for (int nt = 0; nt < 4; nt++) {
        const int c0 = n0 + nt * 16 + lg * 4;
        f32x4 b4 = *(const f32x4*)(biasf + c0);
#pragma unroll
        for (int mt = 0; mt < 4; mt++) {
            const int tok = tok0 + mt * 16 + lq;
            uint2 pv;
            pv.x = pack2bf(fmaxf(acc[mt][nt][0] + b4[0], 0.f),
                           fmaxf(acc[mt][nt][1] + b4[1], 0.f));
            pv.y = pack2bf(fmaxf(acc[mt][nt][2] + b4[2], 0.f),
                           fmaxf(acc[mt][nt][3] + b4[3], 0.f));
            const size_t e = ((size_t)((tok >> 4) * 16 + (c0 >> 5)) * 64 +
                              (((c0 >> 3) & 3) * 16 + lq)) * 8 + (c0 & 7);
            *(uint2*)(hF + e) = pv;
        }
    }
}

// ---------------------------------------------------------------------------
// MLP1 — r4 tiles (MT=2) + T1 XCD swizzle. 1D grid 512. L=(F%8)*64+F/8:
// XCD k gets 16 token-panels x 4 n-tiles; all 4 n-tiles of a panel co-XCD.
// ---------------------------------------------------------------------------
__global__ __launch_bounds__(256) void mlp1_frag(
    const ushort_t* __restrict__ hF, const ushort_t* __restrict__ m1F,
    const float* __restrict__ m1_b, float* __restrict__ out)
{
    const int t = threadIdx.x, w = t >> 6;
    const int lq = t & 15, lg = (t & 63) >> 4;
    const int F = blockIdx.x;                   // [0,512)
    const int L = (F & 7) * 64 + (F >> 3);
    const int m = L % 64;
    const int yy = m >> 2, nx = m & 3;
    const int y = (L / 64) * 16 + yy;           // token panel [0,128)
    const int n0   = nx << 6;
    const int tok0 = (y << 7) + (w << 5);
    const int t16  = tok0 >> 4, n16 = n0 >> 4;

    f32x4 acc[2][4];
#pragma unroll
    for (int mt = 0; mt < 2; mt++)
#pragma unroll
        for (int nt = 0; nt < 4; nt++) acc[mt][nt] = (f32x4){0.f, 0.f, 0.f, 0.f};

    core<16, 16, false, 2>(hF, hF, m1F, t16, n16, acc);

#pragma unroll
    for (int nt = 0; nt < 4; nt++) {
        const int c0 = n0 + nt * 16 + lg * 4;
        f32x4 b4 = *(const f32x4*)(m1_b + c0);
#pragma unroll
        for (int mt = 0; mt < 2; mt++) {
            const int tok = tok0 + mt * 16 + lq;
            f32x4 o4;
#pragma unroll
            for (int j = 0; j < 4; j++) o4[j] = acc[mt][nt][j] + b4[j];
            *(f32x4*)(out + (size_t)tok * ND + c0) = o4;
        }
    }
}

// ---------------------------------------------------------------------------
// Flash cross-attention — r4-proven (60.6us): 32x32x16, key-split, bitmask
// via scalar loads, NO vmcnt drain in the loop. Unchanged.
// ---------------------------------------------------------------------------
__global__ __launch_bounds__(256) void attn_frag(
    const ushort_t* __restrict__ qF, const ushort_t* __restrict__ kF,
    const ushort_t* __restrict__ vF, const uint_t* __restrict__ mbits,
    ushort_t* __restrict__ ctxF)
{
    __shared__ f32x4 Ob[2][2][4][64];   // [wq][dt][r1][lane] partial o (16KB)
    __shared__ float Ls[2][64];         // [wq][lane] partial l (0.5KB)

    const int t = threadIdx.x, w = t >> 6, lane = t & 63;
    const int wq = w & 1, kw = w >> 1;
    const int q = lane & 31, h = lane >> 5;
    // swizzle: flat = x + 32y + 128z in [0,1024)
    const int flat = blockIdx.x + (blockIdx.y << 5) + (blockIdx.z << 7);
    const int bh = (flat & 7) + (((flat >> 8) & 3) << 3);  // [0,32)
    const int qb = (flat >> 3) & 31;                        // [0,32)

    const ushort_t* qh = qF + (size_t)bh * 131072;
    const ushort_t* kh = kF + (size_t)bh * 131072;
    const ushort_t* vh = vF + (size_t)bh * 131072;
    const uint_t* mw = mbits + (bh >> 2) * 64 + (kw << 5);  // 32 words/half

    const int qrow0 = qb * 64 + wq * 32;
    const int tok = qrow0 + q;
    const int kbase = kw << 10;          // this wave's key half

    // Q B-frags (st = 0..3): lane holds Q[tok = qrow0+q][ch = st*16 + 8h + j]
    bf16x8 qf[4];
#pragma unroll
    for (int st = 0; st < 4; st++)
        qf[st] = *(const bf16x8*)(qh +
            ((size_t)(((tok >> 4) * 2 + (st >> 1)) * 64 +
                      ((st * 2 + h) & 3) * 16 + (tok & 15))) * 8);

    f32x16 o[2];
#pragma unroll
    for (int dt = 0; dt < 2; dt++)
#pragma unroll
        for (int j = 0; j < 16; j++) o[dt][j] = 0.f;
    float l_part = 0.0f;

    // preload K A-frags for first chunk of this half
    bf16x8 ka[2][4];
#pragma unroll
    for (int kt = 0; kt < 2; kt++)
#pragma unroll
        for (int st = 0; st < 4; st++) {
            const int key = kbase + kt * 32 + q;
            ka[kt][st] = *(const bf16x8*)(kh +
                ((size_t)(((key >> 4) * 2 + (st >> 1)) * 64 +
                          ((st * 2 + h) & 3) * 16 + (key & 15))) * 8);
        }

    for (int k0 = 0; k0 < 1024; k0 += 64) {
        const int key0 = kbase + k0;

        // V A-frags for THIS chunk: issued at top; consumed after softmax
        // (QK + softmax cover the latency; PV's wait is counted, not drain).
        bf16x8 vf[2][4];
#pragma unroll
        for (int dt = 0; dt < 2; dt++)
#pragma unroll
            for (int st = 0; st < 4; st++) {
                const int d = dt * 32 + q;
                vf[dt][st] = *(const bf16x8*)(vh +
                    ((size_t)(((d >> 4) * 64 + (key0 >> 5) + (st >> 1)) * 64 +
                              ((st * 2 + h) & 3) * 16 + (d & 15))) * 8);
            }

        // wave-uniform mask words (scalar loads -> lgkmcnt, NOT vmcnt)
        const uint_t mw0 = mw[(k0 >> 5)];
        const uint_t mw1 = mw[(k0 >> 5) + 1];

        // QK^T: C[key][q], zero C-init. Wait here is for ka (prefetched a
        // full iteration ago) -> counted vmcnt leaves V(i) in flight.
        f32x16 sa[2];
#pragma unroll
        for (int kt = 0; kt < 2; kt++)
#pragma unroll
            for (int j = 0; j < 16; j++) sa[kt][j] = 0.f;

        __builtin_amdgcn_s_setprio(1);
#pragma unroll
        for (int kt = 0; kt < 2; kt++)
#pragma unroll
            for (int st = 0; st < 4; st++)
                sa[kt] = MFMA32(ka[kt][st], qf[st], sa[kt]);
        __builtin_amdgcn_s_setprio(0);

        // in-place prefetch next chunk's K frags (wrap within half);
        // stays in flight across PV, waited (counted) at next QK.
        const int keyn = kbase + ((k0 + 64) & 1023);
#pragma unroll
        for (int kt = 0; kt < 2; kt++)
#pragma unroll
            for (int st = 0; st < 4; st++) {
                const int key = keyn + kt * 32 + q;
                ka[kt][st] = *(const bf16x8*)(kh +
                    ((size_t)(((key >> 4) * 2 + (st >> 1)) * 64 +
                              ((st * 2 + h) & 3) * 16 + (key & 15))) * 8);
            }

        // softmax numerator (no max-subtract: scores bounded), VMEM-free.
        // mask applied multiplicatively (== additive -1e9) behind a
        // wave-uniform fast-path branch; 4 parallel l accumulators.
        float ls0 = 0.f, ls1 = 0.f, ls2 = 0.f, ls3 = 0.f;
        uint_t W[2][4][2];

#define SMAX_BODY(DM)                                                         \
        _Pragma("unroll")                                                     \
        for (int kt = 0; kt < 2; kt++) {                                      \
            _Pragma("unroll")                                                 \
            for (int r1 = 0; r1 < 4; r1++) {                                  \
                _Pragma("unroll")                                             \
                for (int wv = 0; wv < 2; wv++) {                              \
                    float p0 = EXP2(sa[kt][r1 * 4 + wv * 2]);                 \
                    float p1 = EXP2(sa[kt][r1 * 4 + wv * 2 + 1]);             \
                    if (DM) {                                                 \
                        const uint_t mk = (kt ? mw1 : mw0) >> (h * 4);        \
                        if (!((mk >> (r1 * 8 + wv * 2)) & 1u)) p0 = 0.f;      \
                        if (!((mk >> (r1 * 8 + wv * 2)) & 2u)) p1 = 0.f;      \
                    }                                                         \
                    if (kt == 0) { if (wv == 0) ls0 += p0 + p1;               \
                                   else         ls1 += p0 + p1; }             \
                    else         { if (wv == 0) ls2 += p0 + p1;               \
                                   else         ls3 += p0 + p1; }             \
                    W[kt][r1][wv] = cvtpk_bf16(p0, p1);                       \
                }                                                             \
            }                                                                 \
        }

        if (__builtin_expect((mw0 & mw1) != 0xFFFFFFFFu, 0)) {
            SMAX_BODY(1)
        } else {
            SMAX_BODY(0)
        }
#undef SMAX_BODY
        l_part += (ls0 + ls1) + (ls2 + ls3);

        // half-wave exchange: builds all 16 PV B-operand dwords in 8 swaps
#pragma unroll
        for (int kt = 0; kt < 2; kt++)
#pragma unroll
            for (int s1 = 0; s1 < 2; s1++)
#pragma unroll
                for (int wv = 0; wv < 2; wv++)
                    plswap(W[kt][2 * s1][wv], W[kt][2 * s1 + 1][wv]);

        // ctx^T += V^T · P  (waits V(i) counted; K(i+1) stays in flight)
        __builtin_amdgcn_s_setprio(1);
#pragma unroll
        for (int st = 0; st < 4; st++) {
            const int kt = st >> 1, s1 = st & 1;
            union { uint_t u[4]; bf16x8 v; } pb;
            pb.u[0] = W[kt][2 * s1][0];
            pb.u[1] = W[kt][2 * s1][1];
            pb.u[2] = W[kt][2 * s1 + 1][0];
            pb.u[3] = W[kt][2 * s1 + 1][1];
#pragma unroll
            for (int dt = 0; dt < 2; dt++)
                o[dt] = MFMA32(vf[dt][st], pb.v, o[dt]);
        }
        __builtin_amdgcn_s_setprio(0);
    }

    // per-wave l: lane and lane+32 hold complementary key subsets of the half
    l_part += __shfl_xor(l_part, 32);

    // cross-half combine: kw=1 deposits partials, kw=0 reduces + stores
    if (kw) {
#pragma unroll
        for (int dt = 0; dt < 2; dt++)
#pragma unroll
            for (int r1 = 0; r1 < 4; r1++) {
                f32x4 v;
#pragma unroll
                for (int r0 = 0; r0 < 4; r0++) v[r0] = o[dt][r1 * 4 + r0];
                Ob[wq][dt][r1][lane] = v;
            }
        Ls[wq][lane] = l_part;
    }
    __syncthreads();
    if (kw) return;

    const float li = 1.0f / (l_part + Ls[wq][lane]);

    // epilogue: ctx frag-major bf16.  o[dt] reg r = 4*r1 + r0 is
    // (d = r0 + 8*r1 + 4h + 32*dt, q); each (dt,r1) is one aligned uint2.
    const int tok16 = (bh >> 2) * 128 + (tok >> 4);
#pragma unroll
    for (int dt = 0; dt < 2; dt++)
#pragma unroll
        for (int r1 = 0; r1 < 4; r1++) {
            const f32x4 p = Ob[wq][dt][r1][lane];
            const int c = (bh & 3) * 64 + dt * 32 + r1 * 8 + h * 4;
            uint2 pv;
            pv.x = cvtpk_bf16((o[dt][r1 * 4 + 0] + p[0]) * li,
                              (o[dt][r1 * 4 + 1] + p[1]) * li);
            pv.y = cvtpk_bf16((o[dt][r1 * 4 + 2] + p[2]) * li,
                              (o[dt][r1 * 4 + 3] + p[3]) * li);
            const size_t e = ((size_t)(tok16 * 8 + (c >> 5)) * 64 +
                              (((c >> 3) & 3) * 16 + (tok & 15))) * 8 + (c & 7);
            *(uint2*)(ctxF + e) = pv;
        }
}

extern "C" void kernel_launch(void* const* d_in, const int* in_sizes, int n_in,
                              void* d_out, int out_size, void* d_ws, size_t ws_size,
                              hipStream_t stream)
{
    (void)in_sizes; (void)n_in; (void)out_size; (void)ws_size;
    const float* desc = (const float*)d_in[0];
    const float* srcp = (const float*)d_in[1];
    const int*   mask = (const int*)d_in[2];
    const float* q_w  = (const float*)d_in[3];
    const float* q_b  = (const float*)d_in[4];
    const float* k_w  = (const float*)d_in[5];
    const float* k_b  = (const float*)d_in[6];
    const float* v_w  = (const float*)d_in[7];
    const float* v_b  = (const float*)d_in[8];
    const float* o_w  = (const float*)d_in[9];
    const float* o_b  = (const float*)d_in[10];
    const float* m0_w = (const float*)d_in[11];
    const float* m0_b = (const float*)d_in[12];
    const float* bng  = (const float*)d_in[13];
    const float* bnb  = (const float*)d_in[14];
    const float* bnm  = (const float*)d_in[15];
    const float* bnv  = (const float*)d_in[16];
    const float* m1_w = (const float*)d_in[17];
    const float* m1_b = (const float*)d_in[18];
    float* out = (float*)d_out;

    const size_t ASZ = (size_t)NM * ND;
    ushort_t* descF = (ushort_t*)d_ws;
    ushort_t* srcF  = descF + ASZ;
    ushort_t* qF    = descF + 2 * ASZ;
    ushort_t* kF    = descF + 3 * ASZ;
    ushort_t* vF    = descF + 4 * ASZ;
    ushort_t* qwF   = descF + 5 * ASZ;
    ushort_t* kwF   = qwF + 65536;
    ushort_t* vwF   = kwF + 65536;
    ushort_t* m1F   = vwF + 65536;
    ushort_t* m0fF  = m1F + 131072;
    float*    biasf = (float*)(m0fF + 262144);
    uint_t*   mbits = (uint_t*)(biasf + 512);
    ushort_t* ctxF  = srcF;   // src dead after QKV
    ushort_t* hF    = qF;     // q+k dead after attention

    const dim3 blk(256);

    prep<<<dim3(4626), blk, 0, stream>>>(
        desc, srcp, mask, q_w, k_w, v_w, m1_w, o_w, o_b, m0_w, m0_b,
        bng, bnb, bnm, bnv, descF, srcF, qwF, kwF, vwF, m1F, m0fF, biasf, mbits);

    qkv_frag<<<dim3(768), blk, 0, stream>>>(
        descF, srcF, qwF, kwF, vwF, q_b, k_b, v_b, qF, kF, vF);
    attn_frag<<<dim3(NS / 64, NH, NB), blk, 0, stream>>>(qF, kF, vF, mbits, ctxF);
    mlp0_frag<<<dim3(512), blk, 0, stream>>>(descF, ctxF, m0fF, biasf, hF);
    mlp1_frag<<<dim3(512), blk, 0, stream>>>(hF, m1F, m1_b, out);
}